// Round 1
// baseline (1331.122 us; speedup 1.0000x reference)
//
#include <hip/hip_runtime.h>
#include <hip/hip_bf16.h>

#define EPS 1e-5f

// ---------------------------------------------------------------- CSR build
__global__ void count_deg_kernel(const int* __restrict__ dst, int* __restrict__ deg, int E) {
    int e = blockIdx.x * 256 + threadIdx.x;
    if (e < E) atomicAdd(&deg[dst[e]], 1);
}

__global__ void block_sums_kernel(const int* __restrict__ deg, int* __restrict__ bsums, int n) {
    int i = blockIdx.x * 256 + threadIdx.x;
    int v = (i < n) ? deg[i] : 0;
#pragma unroll
    for (int d = 32; d > 0; d >>= 1) v += __shfl_down(v, d);
    __shared__ int ws[4];
    int lane = threadIdx.x & 63, w = threadIdx.x >> 6;
    if (lane == 0) ws[w] = v;
    __syncthreads();
    if (threadIdx.x == 0) bsums[blockIdx.x] = ws[0] + ws[1] + ws[2] + ws[3];
}

// single block, 512 threads: in-place exclusive scan of bsums[0..nb)
__global__ void scan_bsums_kernel(int* bsums, int nb) {
    int t = threadIdx.x;
    int orig = (t < nb) ? bsums[t] : 0;
    int v = orig;
    int lane = t & 63, w = t >> 6;
#pragma unroll
    for (int d = 1; d < 64; d <<= 1) { int u = __shfl_up(v, d); if (lane >= d) v += u; }
    __shared__ int wsum[8];
    if (lane == 63) wsum[w] = v;
    __syncthreads();
    int off = 0;
    for (int i = 0; i < w; ++i) off += wsum[i];
    if (t < nb) bsums[t] = off + v - orig;   // exclusive
}

__global__ void scan_final_kernel(const int* __restrict__ deg, const int* __restrict__ bsums,
                                  int* __restrict__ rowptr, int n) {
    int i = blockIdx.x * 256 + threadIdx.x;
    int orig = (i < n) ? deg[i] : 0;
    int v = orig;
    int lane = threadIdx.x & 63, w = threadIdx.x >> 6;
#pragma unroll
    for (int d = 1; d < 64; d <<= 1) { int u = __shfl_up(v, d); if (lane >= d) v += u; }
    __shared__ int wsum[4];
    if (lane == 63) wsum[w] = v;
    __syncthreads();
    int off = bsums[blockIdx.x];
    for (int k = 0; k < w; ++k) off += wsum[k];
    if (i <= n) rowptr[i] = off + v - orig;  // exclusive; rowptr[n] = E
}

__global__ void copy_kernel(const int* __restrict__ a, int* __restrict__ b, int n) {
    int i = blockIdx.x * 256 + threadIdx.x;
    if (i < n) b[i] = a[i];
}

__global__ void fill_kernel(const int* __restrict__ src, const int* __restrict__ dst,
                            int* cursor, int* __restrict__ eidx, int E) {
    int e = blockIdx.x * 256 + threadIdx.x;
    if (e < E) {
        int slot = atomicAdd(&cursor[dst[e]], 1);
        eidx[slot] = src[e];
    }
}

// ---------------------------------------------------------------- layer 1 (Cin = 1)
__global__ void gather1_kernel(const float* __restrict__ x, const int* __restrict__ rowptr,
                               const int* __restrict__ eidx, float* __restrict__ agg1, int n) {
    int i = blockIdx.x * 256 + threadIdx.x;
    if (i >= n) return;
    float acc = 0.f;
    int e0 = rowptr[i], e1 = rowptr[i + 1];
    for (int e = e0; e < e1; ++e) acc += x[eidx[e]];
    agg1[i] = acc;
}

__global__ void layer1_kernel(const float* __restrict__ x, const float* __restrict__ agg1,
                              const float* __restrict__ Wrel, const float* __restrict__ brel,
                              const float* __restrict__ Wroot,
                              const float* __restrict__ gamma, const float* __restrict__ beta,
                              const float* __restrict__ mean, const float* __restrict__ var,
                              float* __restrict__ h1, int n) {
    int idx = blockIdx.x * 256 + threadIdx.x;
    int i = idx >> 7, c = idx & 127;
    if (i >= n) return;
    float s = gamma[c] * rsqrtf(var[c] + EPS);
    float t = beta[c] - mean[c] * s;
    float v = agg1[i] * Wrel[c] + brel[c] + x[i] * Wroot[c];
    v = v * s + t;
    h1[idx] = fmaxf(v, 0.f);
}

// ---------------------------------------------------------------- weight transpose (128x128)
__global__ void transpose128_kernel(const float* __restrict__ W, float* __restrict__ WT) {
    int idx = blockIdx.x * 256 + threadIdx.x;   // 16384 threads
    int c = idx >> 7, k = idx & 127;
    WT[k * 128 + c] = W[c * 128 + k];
}

// ---------------------------------------------------------------- heavy aggregation (H=128)
__global__ __launch_bounds__(256) void gather_agg_kernel(const float* __restrict__ h,
                                                         const int* __restrict__ rowptr,
                                                         const int* __restrict__ eidx,
                                                         float* __restrict__ agg, int n) {
    int node = blockIdx.x * 2 + (threadIdx.x >> 7);
    int c = threadIdx.x & 127;
    if (node >= n) return;
    int e0 = rowptr[node], e1 = rowptr[node + 1];
    float acc = 0.f;
    int e = e0;
    for (; e + 4 <= e1; e += 4) {
        int s0 = eidx[e], s1 = eidx[e + 1], s2 = eidx[e + 2], s3 = eidx[e + 3];
        float v0 = h[s0 * 128 + c];
        float v1 = h[s1 * 128 + c];
        float v2 = h[s2 * 128 + c];
        float v3 = h[s3 * 128 + c];
        acc += (v0 + v1) + (v2 + v3);
    }
    for (; e < e1; ++e) acc += h[eidx[e] * 128 + c];
    agg[node * 128 + c] = acc;
}

// ---------------------------------------------------------------- fused conv: out = BN(agg@WrelT + b + h@WrootT) [+relu]
template <int RELU>
__global__ __launch_bounds__(256) void conv_fused_kernel(
    const float* __restrict__ agg, const float* __restrict__ hin,
    const float* __restrict__ WrelT, const float* __restrict__ WrootT,
    const float* __restrict__ brel,
    const float* __restrict__ gamma, const float* __restrict__ beta,
    const float* __restrict__ mean, const float* __restrict__ var,
    float* __restrict__ hout, int n) {
    __shared__ float sA[64 * 128];
    __shared__ float sH[64 * 128];
    const int tid = threadIdx.x;
    const int base = blockIdx.x * 64;

    // stage 64-node tiles of agg and hin
    for (int idx = tid * 4; idx < 64 * 128; idx += 1024) {
        int node = base + (idx >> 7);
        float4 a, h;
        if (node < n) {
            a = *(const float4*)&agg[base * 128 + idx];
            h = *(const float4*)&hin[base * 128 + idx];
        } else {
            a = make_float4(0.f, 0.f, 0.f, 0.f);
            h = a;
        }
        *(float4*)&sA[idx] = a;
        *(float4*)&sH[idx] = h;
    }
    __syncthreads();

    const int cg = tid & 31;   // channels cg*4 .. cg*4+3
    const int ng = tid >> 5;   // nodes ng*8 .. ng*8+7
    float acc[8][4] = {};

    for (int k = 0; k < 128; k += 2) {
        float4 wr0 = *(const float4*)&WrelT[k * 128 + cg * 4];
        float4 wr1 = *(const float4*)&WrelT[(k + 1) * 128 + cg * 4];
        float4 wo0 = *(const float4*)&WrootT[k * 128 + cg * 4];
        float4 wo1 = *(const float4*)&WrootT[(k + 1) * 128 + cg * 4];
#pragma unroll
        for (int j = 0; j < 8; ++j) {
            float2 a = *(const float2*)&sA[(ng * 8 + j) * 128 + k];
            float2 h = *(const float2*)&sH[(ng * 8 + j) * 128 + k];
            acc[j][0] += a.x * wr0.x + a.y * wr1.x + h.x * wo0.x + h.y * wo1.x;
            acc[j][1] += a.x * wr0.y + a.y * wr1.y + h.x * wo0.y + h.y * wo1.y;
            acc[j][2] += a.x * wr0.z + a.y * wr1.z + h.x * wo0.z + h.y * wo1.z;
            acc[j][3] += a.x * wr0.w + a.y * wr1.w + h.x * wo0.w + h.y * wo1.w;
        }
    }

    float s[4], t[4], bb[4];
#pragma unroll
    for (int q = 0; q < 4; ++q) {
        int c = cg * 4 + q;
        float sc = gamma[c] * rsqrtf(var[c] + EPS);
        s[q] = sc;
        t[q] = beta[c] - mean[c] * sc;
        bb[q] = brel[c];
    }
#pragma unroll
    for (int j = 0; j < 8; ++j) {
        int node = base + ng * 8 + j;
        if (node >= n) break;
        float4 o;
        o.x = (acc[j][0] + bb[0]) * s[0] + t[0];
        o.y = (acc[j][1] + bb[1]) * s[1] + t[1];
        o.z = (acc[j][2] + bb[2]) * s[2] + t[2];
        o.w = (acc[j][3] + bb[3]) * s[3] + t[3];
        if (RELU) {
            o.x = fmaxf(o.x, 0.f); o.y = fmaxf(o.y, 0.f);
            o.z = fmaxf(o.z, 0.f); o.w = fmaxf(o.w, 0.f);
        }
        *(float4*)&hout[node * 128 + cg * 4] = o;
    }
}

// ---------------------------------------------------------------- pooling (batch sorted)
__global__ void pool_partial_kernel(const float* __restrict__ h, const int* __restrict__ batch,
                                    float* __restrict__ sums, int* __restrict__ cnt, int n) {
    int c = threadIdx.x;                 // 0..127
    int start = blockIdx.x * 512;
    if (start >= n) return;
    int end = min(start + 512, n);
    float acc = 0.f;
    int cur = batch[start];
    int cl = 0;
    for (int i = start; i < end; ++i) {
        int g = batch[i];
        if (g != cur) {
            atomicAdd(&sums[cur * 128 + c], acc);
            if (c == 0) atomicAdd(&cnt[cur], cl);
            acc = 0.f; cl = 0; cur = g;
        }
        acc += h[i * 128 + c];
        cl++;
    }
    atomicAdd(&sums[cur * 128 + c], acc);
    if (c == 0) atomicAdd(&cnt[cur], cl);
}

__global__ void out_kernel(const float* __restrict__ sums, const int* __restrict__ cnt,
                           const float* __restrict__ Wout, const float* __restrict__ bout,
                           float* __restrict__ out) {
    int g = blockIdx.x, t = threadIdx.x;   // 128 threads
    float cn = fmaxf((float)cnt[g], 1.0f);
    float v = sums[g * 128 + t] / cn * Wout[t];
#pragma unroll
    for (int d = 32; d > 0; d >>= 1) v += __shfl_down(v, d);
    __shared__ float ws2[2];
    if ((t & 63) == 0) ws2[t >> 6] = v;
    __syncthreads();
    if (t == 0) out[g] = ws2[0] + ws2[1] + bout[0];
}

// ---------------------------------------------------------------- launch
extern "C" void kernel_launch(void* const* d_in, const int* in_sizes, int n_in,
                              void* d_out, int out_size, void* d_ws, size_t ws_size,
                              hipStream_t stream) {
    const int N = in_sizes[0];
    const int E = in_sizes[1] / 2;
    const int G = 64;

    const float* x     = (const float*)d_in[0];
    const int*   ei    = (const int*)d_in[1];
    const int*   batch = (const int*)d_in[2];
    const int*   src   = ei;
    const int*   dst   = ei + E;

    const float* Wrel1 = (const float*)d_in[3];
    const float* brel1 = (const float*)d_in[4];
    const float* Wroot1= (const float*)d_in[5];
    const float* g1    = (const float*)d_in[6];
    const float* be1   = (const float*)d_in[7];
    const float* m1    = (const float*)d_in[8];
    const float* v1    = (const float*)d_in[9];
    const float* Wrel2 = (const float*)d_in[10];
    const float* brel2 = (const float*)d_in[11];
    const float* Wroot2= (const float*)d_in[12];
    const float* g2    = (const float*)d_in[13];
    const float* be2   = (const float*)d_in[14];
    const float* m2    = (const float*)d_in[15];
    const float* v2    = (const float*)d_in[16];
    const float* Wrel3 = (const float*)d_in[17];
    const float* brel3 = (const float*)d_in[18];
    const float* Wroot3= (const float*)d_in[19];
    const float* g3    = (const float*)d_in[20];
    const float* be3   = (const float*)d_in[21];
    const float* m3    = (const float*)d_in[22];
    const float* v3    = (const float*)d_in[23];
    const float* Wout  = (const float*)d_in[24];
    const float* bout  = (const float*)d_in[25];

    float* out = (float*)d_out;

    // workspace carve (512B aligned)
    char* w = (char*)d_ws;
    auto alloc = [&](size_t bytes) { char* p = w; w += (bytes + 511) & ~(size_t)511; return p; };
    int*   rowptr = (int*)alloc((size_t)(N + 1) * 4);
    int*   deg    = (int*)alloc((size_t)N * 4);
    int*   cursor = (int*)alloc((size_t)N * 4);
    int*   bsums  = (int*)alloc(4096);
    int*   eidx   = (int*)alloc((size_t)E * 4);
    float* agg1   = (float*)alloc((size_t)N * 4);
    float* hA     = (float*)alloc((size_t)N * 128 * 4);
    float* hB     = (float*)alloc((size_t)N * 128 * 4);
    float* aggb   = (float*)alloc((size_t)N * 128 * 4);
    float* WrelT2 = (float*)alloc(65536);
    float* WrootT2= (float*)alloc(65536);
    float* WrelT3 = (float*)alloc(65536);
    float* WrootT3= (float*)alloc(65536);
    float* gsums  = (float*)alloc((size_t)G * 128 * 4);
    int*   gcnt   = (int*)alloc((size_t)G * 4);

    const int nBlk256  = (N + 1 + 255) / 256;           // covers N+1 entries (391)
    const int eBlk     = (E + 255) / 256;

    hipMemsetAsync(deg, 0, (size_t)N * 4, stream);
    hipMemsetAsync(gsums, 0, (size_t)G * 128 * 4, stream);
    hipMemsetAsync(gcnt, 0, (size_t)G * 4, stream);

    // CSR build
    count_deg_kernel<<<eBlk, 256, 0, stream>>>(dst, deg, E);
    block_sums_kernel<<<nBlk256, 256, 0, stream>>>(deg, bsums, N);
    scan_bsums_kernel<<<1, 512, 0, stream>>>(bsums, nBlk256);
    scan_final_kernel<<<nBlk256, 256, 0, stream>>>(deg, bsums, rowptr, N);
    copy_kernel<<<nBlk256, 256, 0, stream>>>(rowptr, cursor, N);
    fill_kernel<<<eBlk, 256, 0, stream>>>(src, dst, cursor, eidx, E);

    // weight transposes
    transpose128_kernel<<<64, 256, 0, stream>>>(Wrel2, WrelT2);
    transpose128_kernel<<<64, 256, 0, stream>>>(Wroot2, WrootT2);
    transpose128_kernel<<<64, 256, 0, stream>>>(Wrel3, WrelT3);
    transpose128_kernel<<<64, 256, 0, stream>>>(Wroot3, WrootT3);

    // layer 1
    gather1_kernel<<<(N + 255) / 256, 256, 0, stream>>>(x, rowptr, eidx, agg1, N);
    layer1_kernel<<<(N * 128 + 255) / 256, 256, 0, stream>>>(x, agg1, Wrel1, brel1, Wroot1,
                                                             g1, be1, m1, v1, hA, N);

    // layer 2
    gather_agg_kernel<<<(N + 1) / 2, 256, 0, stream>>>(hA, rowptr, eidx, aggb, N);
    conv_fused_kernel<1><<<(N + 63) / 64, 256, 0, stream>>>(aggb, hA, WrelT2, WrootT2, brel2,
                                                            g2, be2, m2, v2, hB, N);

    // layer 3
    gather_agg_kernel<<<(N + 1) / 2, 256, 0, stream>>>(hB, rowptr, eidx, aggb, N);
    conv_fused_kernel<0><<<(N + 63) / 64, 256, 0, stream>>>(aggb, hB, WrelT3, WrootT3, brel3,
                                                            g3, be3, m3, v3, hA, N);

    // pool + output
    pool_partial_kernel<<<(N + 511) / 512, 128, 0, stream>>>(hA, batch, gsums, gcnt, N);
    out_kernel<<<G, 128, 0, stream>>>(gsums, gcnt, Wout, bout, out);
}

// Round 2
// 793.925 us; speedup vs baseline: 1.6766x; 1.6766x over previous
//
#include <hip/hip_runtime.h>

typedef unsigned int uint;
typedef unsigned short ushort;

#define EPS 1e-5f
#define BSH 11   // bucket = 2048 dst nodes

typedef __attribute__((ext_vector_type(8))) short short8;
typedef __attribute__((ext_vector_type(16))) float f32x16;

static __device__ __forceinline__ ushort f2b(float f) {
    uint u = __float_as_uint(f);
    u = (u + 0x7fffu + ((u >> 16) & 1u)) >> 16;
    return (ushort)u;
}
static __device__ __forceinline__ float b2f(ushort b) {
    return __uint_as_float(((uint)b) << 16);
}

// ---------------------------------------------------------------- CSR: degree + scan
__global__ void count_deg_kernel(const int* __restrict__ dst, int* __restrict__ deg, int E) {
    int e = blockIdx.x * 256 + threadIdx.x;
    if (e < E) atomicAdd(&deg[dst[e]], 1);
}

__global__ void block_sums_kernel(const int* __restrict__ deg, int* __restrict__ bsums, int n) {
    int i = blockIdx.x * 256 + threadIdx.x;
    int v = (i < n) ? deg[i] : 0;
#pragma unroll
    for (int d = 32; d > 0; d >>= 1) v += __shfl_down(v, d);
    __shared__ int ws[4];
    int lane = threadIdx.x & 63, w = threadIdx.x >> 6;
    if (lane == 0) ws[w] = v;
    __syncthreads();
    if (threadIdx.x == 0) bsums[blockIdx.x] = ws[0] + ws[1] + ws[2] + ws[3];
}

__global__ void scan_bsums_kernel(int* bsums, int nb) {
    int t = threadIdx.x;
    int orig = (t < nb) ? bsums[t] : 0;
    int v = orig;
    int lane = t & 63, w = t >> 6;
#pragma unroll
    for (int d = 1; d < 64; d <<= 1) { int u = __shfl_up(v, d); if (lane >= d) v += u; }
    __shared__ int wsum[8];
    if (lane == 63) wsum[w] = v;
    __syncthreads();
    int off = 0;
    for (int i = 0; i < w; ++i) off += wsum[i];
    if (t < nb) bsums[t] = off + v - orig;   // exclusive
}

__global__ void scan_final_kernel(const int* __restrict__ deg, const int* __restrict__ bsums,
                                  int* __restrict__ rowptr, int n) {
    int i = blockIdx.x * 256 + threadIdx.x;
    int orig = (i < n) ? deg[i] : 0;
    int v = orig;
    int lane = threadIdx.x & 63, w = threadIdx.x >> 6;
#pragma unroll
    for (int d = 1; d < 64; d <<= 1) { int u = __shfl_up(v, d); if (lane >= d) v += u; }
    __shared__ int wsum[4];
    if (lane == 63) wsum[w] = v;
    __syncthreads();
    int off = bsums[blockIdx.x];
    for (int k = 0; k < w; ++k) off += wsum[k];
    if (i <= n) rowptr[i] = off + v - orig;  // exclusive; rowptr[n] = E
}

__global__ void copy_kernel(const int* __restrict__ a, int* __restrict__ b, int n) {
    int i = blockIdx.x * 256 + threadIdx.x;
    if (i < n) b[i] = a[i];
}

__global__ void gcur_init_kernel(const int* __restrict__ rowptr, int* __restrict__ gcur,
                                 int nb, int n) {
    int b = threadIdx.x;
    if (b < nb) {
        int d = b << BSH;
        gcur[b] = rowptr[d > n ? n : d];
    }
}

// ---------------------------------------------------------------- bucket sort pass A
// Bin edges into contiguous dst-buckets (2048 dsts each); writes are sequential runs.
__global__ __launch_bounds__(256) void bucketA_kernel(const int* __restrict__ src,
                                                      const int* __restrict__ dst,
                                                      int* __restrict__ gcur,
                                                      int2* __restrict__ stage, int E) {
    __shared__ int lh[64];
    __shared__ int lbase[64];
    const int tid = threadIdx.x;
    const int base = blockIdx.x * 8192;
    const int end = min(base + 8192, E);
    if (tid < 64) lh[tid] = 0;
    __syncthreads();
    for (int i = base + tid; i < end; i += 256) atomicAdd(&lh[dst[i] >> BSH], 1);
    __syncthreads();
    if (tid < 64) {
        int c = lh[tid];
        lbase[tid] = c ? atomicAdd(&gcur[tid], c) : 0;
        lh[tid] = 0;
    }
    __syncthreads();
    for (int i = base + tid; i < end; i += 256) {
        int d = dst[i];
        int b = d >> BSH;
        int pos = lbase[b] + atomicAdd(&lh[b], 1);
        stage[pos] = make_int2(src[i], d);
    }
}

// ---------------------------------------------------------------- bucket sort pass B
// Per bucket: final CSR placement. Write region (~260KB) is L2-resident; all
// sub-blocks of a bucket share blockIdx%8 -> same XCD (heuristic).
__global__ __launch_bounds__(256) void bucketB_kernel(const int2* __restrict__ stage,
                                                      const int* __restrict__ rowptr,
                                                      int* __restrict__ cursor,
                                                      int* __restrict__ eidx,
                                                      int nb, int nb8, int n) {
    const int b = blockIdx.x % nb8;
    const int s = blockIdx.x / nb8;
    if (b >= nb) return;
    int d0 = b << BSH, d1 = (b + 1) << BSH;
    if (d0 > n) d0 = n;
    if (d1 > n) d1 = n;
    const int r0 = rowptr[d0];
    const int r1 = rowptr[d1];
    const int len = r1 - r0;
    const int lo = r0 + (int)((long long)len * s / 16);
    const int hi = r0 + (int)((long long)len * (s + 1) / 16);
    for (int i = lo + threadIdx.x; i < hi; i += 256) {
        int2 p = stage[i];
        int slot = atomicAdd(&cursor[p.y], 1);
        eidx[slot] = p.x;
    }
}

// ---------------------------------------------------------------- layer 1 (Cin = 1)
__global__ void gather1_kernel(const float* __restrict__ x, const int* __restrict__ rowptr,
                               const int* __restrict__ eidx, float* __restrict__ agg1, int n) {
    int i = blockIdx.x * 256 + threadIdx.x;
    if (i >= n) return;
    float acc = 0.f;
    int e0 = rowptr[i], e1 = rowptr[i + 1];
    for (int e = e0; e < e1; ++e) acc += x[eidx[e]];
    agg1[i] = acc;
}

__global__ void layer1_kernel(const float* __restrict__ x, const float* __restrict__ agg1,
                              const float* __restrict__ Wrel, const float* __restrict__ brel,
                              const float* __restrict__ Wroot,
                              const float* __restrict__ gamma, const float* __restrict__ beta,
                              const float* __restrict__ mean, const float* __restrict__ var,
                              ushort* __restrict__ h1, int n) {
    int idx = blockIdx.x * 256 + threadIdx.x;
    int i = idx >> 7, c = idx & 127;
    if (i >= n) return;
    float s = gamma[c] * rsqrtf(var[c] + EPS);
    float t = beta[c] - mean[c] * s;
    float v = agg1[i] * Wrel[c] + brel[c] + x[i] * Wroot[c];
    v = v * s + t;
    h1[idx] = f2b(fmaxf(v, 0.f));
}

// ---------------------------------------------------------------- aggregation (bf16, H=128)
__global__ __launch_bounds__(256) void gather_bf16_kernel(const ushort* __restrict__ h,
                                                          const int* __restrict__ rowptr,
                                                          const int* __restrict__ eidx,
                                                          ushort* __restrict__ agg, int n) {
    int node = blockIdx.x * 4 + (threadIdx.x >> 6);
    if (node >= n) return;
    int lane = threadIdx.x & 63;
    const uint* hu = (const uint*)h;
    int e0 = rowptr[node], e1 = rowptr[node + 1];
    float a0 = 0.f, a1 = 0.f;
    int e = e0;
    for (; e + 4 <= e1; e += 4) {
        int s0 = eidx[e], s1 = eidx[e + 1], s2 = eidx[e + 2], s3 = eidx[e + 3];
        uint u0 = hu[s0 * 64 + lane];
        uint u1 = hu[s1 * 64 + lane];
        uint u2 = hu[s2 * 64 + lane];
        uint u3 = hu[s3 * 64 + lane];
        a0 += (__uint_as_float(u0 << 16) + __uint_as_float(u1 << 16)) +
              (__uint_as_float(u2 << 16) + __uint_as_float(u3 << 16));
        a1 += (__uint_as_float(u0 & 0xffff0000u) + __uint_as_float(u1 & 0xffff0000u)) +
              (__uint_as_float(u2 & 0xffff0000u) + __uint_as_float(u3 & 0xffff0000u));
    }
    for (; e < e1; ++e) {
        uint u = hu[eidx[e] * 64 + lane];
        a0 += __uint_as_float(u << 16);
        a1 += __uint_as_float(u & 0xffff0000u);
    }
    uint o = (uint)f2b(a0) | ((uint)f2b(a1) << 16);
    ((uint*)agg)[node * 64 + lane] = o;
}

// ---------------------------------------------------------------- weight fragment prep
// WF layout: [half][kt 0..7][ct 0..3][lane 0..63][j 0..7]  (bf16)
// frag element = W_half[ct*32 + (lane&31)][kt*16 + (lane>>5)*8 + j]
__global__ void wf_prep_kernel(const float* __restrict__ W0, const float* __restrict__ W1,
                               const float* __restrict__ W2, const float* __restrict__ W3,
                               ushort* __restrict__ WF2, ushort* __restrict__ WF3) {
    int i = blockIdx.x * 256 + threadIdx.x;   // 65536 threads
    const float* Ws[4] = {W0, W1, W2, W3};
    int mat = i >> 14;
    int m = i & 16383;
    int j = m & 7, lane = (m >> 3) & 63, ct = (m >> 9) & 3, kt = (m >> 11) & 7;
    int row = ct * 32 + (lane & 31);
    int col = kt * 16 + ((lane >> 5) * 8) + j;
    float v = Ws[mat][row * 128 + col];
    ushort* dstp = (mat < 2) ? WF2 : WF3;
    dstp[(mat & 1) * 16384 + m] = f2b(v);
}

// ---------------------------------------------------------------- fused conv via MFMA
// out = BN(agg@Wrel^T + b + h@Wroot^T) [+relu], one K=256 GEMM per node tile.
template <int RELU>
__global__ __launch_bounds__(256) void conv_mfma_kernel(
    const short* __restrict__ agg, const short* __restrict__ hin,
    const short* __restrict__ WF,
    const float* __restrict__ brel, const float* __restrict__ gamma,
    const float* __restrict__ beta, const float* __restrict__ mean,
    const float* __restrict__ var,
    ushort* __restrict__ hout, int n) {
    const int lane = threadIdx.x & 63;
    const int wt = blockIdx.x * 4 + (threadIdx.x >> 6);
    const int node0 = wt * 32;
    if (node0 >= n) return;
    const int rowA = node0 + (lane & 31);
    const int arow = (rowA < n) ? rowA : (n - 1);
    const int koff = (lane >> 5) * 8;

    f32x16 acc[4];
#pragma unroll
    for (int c = 0; c < 4; ++c) acc[c] = (f32x16)(0.0f);

#pragma unroll
    for (int half = 0; half < 2; ++half) {
        const short* A = (half ? hin : agg) + (size_t)arow * 128 + koff;
        const short* B0 = WF + half * 16384 + lane * 8;
#pragma unroll
        for (int kt = 0; kt < 8; ++kt) {
            short8 a = *(const short8*)(A + kt * 16);
            const short* Bp = B0 + kt * 2048;
#pragma unroll
            for (int ct = 0; ct < 4; ++ct) {
                short8 b = *(const short8*)(Bp + ct * 512);
                acc[ct] = __builtin_amdgcn_mfma_f32_32x32x16_bf16(a, b, acc[ct], 0, 0, 0);
            }
        }
    }

#pragma unroll
    for (int ct = 0; ct < 4; ++ct) {
        int c = ct * 32 + (lane & 31);
        float s = gamma[c] * rsqrtf(var[c] + EPS);
        float t = beta[c] - mean[c] * s + brel[c] * s;
#pragma unroll
        for (int r = 0; r < 16; ++r) {
            int row = (r & 3) + 8 * (r >> 2) + 4 * (lane >> 5);
            int node = node0 + row;
            if (node < n) {
                float v = acc[ct][r] * s + t;
                if (RELU) v = fmaxf(v, 0.f);
                hout[(size_t)node * 128 + c] = f2b(v);
            }
        }
    }
}

// ---------------------------------------------------------------- pooling (batch sorted)
__global__ void pool_partial_kernel(const ushort* __restrict__ h, const int* __restrict__ batch,
                                    float* __restrict__ sums, int* __restrict__ cnt, int n) {
    int c = threadIdx.x;                 // 0..127
    int start = blockIdx.x * 512;
    if (start >= n) return;
    int end = min(start + 512, n);
    float acc = 0.f;
    int cur = batch[start];
    int cl = 0;
    for (int i = start; i < end; ++i) {
        int g = batch[i];
        if (g != cur) {
            atomicAdd(&sums[cur * 128 + c], acc);
            if (c == 0) atomicAdd(&cnt[cur], cl);
            acc = 0.f; cl = 0; cur = g;
        }
        acc += b2f(h[(size_t)i * 128 + c]);
        cl++;
    }
    atomicAdd(&sums[cur * 128 + c], acc);
    if (c == 0) atomicAdd(&cnt[cur], cl);
}

__global__ void out_kernel(const float* __restrict__ sums, const int* __restrict__ cnt,
                           const float* __restrict__ Wout, const float* __restrict__ bout,
                           float* __restrict__ out) {
    int g = blockIdx.x, t = threadIdx.x;   // 128 threads
    float cn = fmaxf((float)cnt[g], 1.0f);
    float v = sums[g * 128 + t] / cn * Wout[t];
#pragma unroll
    for (int d = 32; d > 0; d >>= 1) v += __shfl_down(v, d);
    __shared__ float ws2[2];
    if ((t & 63) == 0) ws2[t >> 6] = v;
    __syncthreads();
    if (t == 0) out[g] = ws2[0] + ws2[1] + bout[0];
}

// ---------------------------------------------------------------- launch
extern "C" void kernel_launch(void* const* d_in, const int* in_sizes, int n_in,
                              void* d_out, int out_size, void* d_ws, size_t ws_size,
                              hipStream_t stream) {
    const int N = in_sizes[0];
    const int E = in_sizes[1] / 2;
    const int G = 64;

    const float* x     = (const float*)d_in[0];
    const int*   ei    = (const int*)d_in[1];
    const int*   batch = (const int*)d_in[2];
    const int*   src   = ei;
    const int*   dst   = ei + E;

    const float* Wrel1 = (const float*)d_in[3];
    const float* brel1 = (const float*)d_in[4];
    const float* Wroot1= (const float*)d_in[5];
    const float* g1    = (const float*)d_in[6];
    const float* be1   = (const float*)d_in[7];
    const float* m1    = (const float*)d_in[8];
    const float* v1    = (const float*)d_in[9];
    const float* Wrel2 = (const float*)d_in[10];
    const float* brel2 = (const float*)d_in[11];
    const float* Wroot2= (const float*)d_in[12];
    const float* g2    = (const float*)d_in[13];
    const float* be2   = (const float*)d_in[14];
    const float* m2    = (const float*)d_in[15];
    const float* v2    = (const float*)d_in[16];
    const float* Wrel3 = (const float*)d_in[17];
    const float* brel3 = (const float*)d_in[18];
    const float* Wroot3= (const float*)d_in[19];
    const float* g3    = (const float*)d_in[20];
    const float* be3   = (const float*)d_in[21];
    const float* m3    = (const float*)d_in[22];
    const float* v3    = (const float*)d_in[23];
    const float* Wout  = (const float*)d_in[24];
    const float* bout  = (const float*)d_in[25];

    float* out = (float*)d_out;

    // workspace carve (512B aligned)
    char* w = (char*)d_ws;
    auto alloc = [&](size_t bytes) { char* p = w; w += (bytes + 511) & ~(size_t)511; return p; };
    int*    rowptr = (int*)alloc((size_t)(N + 1) * 4);
    int*    deg    = (int*)alloc((size_t)N * 4);
    int*    cursor = (int*)alloc((size_t)N * 4);
    int*    bsums  = (int*)alloc(4096);
    int*    gcur   = (int*)alloc(1024);
    int*    eidx   = (int*)alloc((size_t)E * 4);
    int2*   stage  = (int2*)alloc((size_t)E * 8);
    float*  agg1   = (float*)alloc((size_t)N * 4);
    ushort* hA     = (ushort*)alloc((size_t)N * 128 * 2);
    ushort* hB     = (ushort*)alloc((size_t)N * 128 * 2);
    ushort* aggb   = (ushort*)alloc((size_t)N * 128 * 2);
    ushort* WF2    = (ushort*)alloc(32768 * 2);
    ushort* WF3    = (ushort*)alloc(32768 * 2);
    float*  gsums  = (float*)alloc((size_t)G * 128 * 4);
    int*    gcnt   = (int*)alloc((size_t)G * 4);

    const int nBlk256 = (N + 1 + 255) / 256;
    const int eBlk    = (E + 255) / 256;
    const int nb      = (N + (1 << BSH) - 1) >> BSH;
    const int nb8     = (nb + 7) & ~7;

    hipMemsetAsync(deg, 0, (size_t)N * 4, stream);
    hipMemsetAsync(gsums, 0, (size_t)G * 128 * 4, stream);
    hipMemsetAsync(gcnt, 0, (size_t)G * 4, stream);

    // CSR build: degree + rowptr scan
    count_deg_kernel<<<eBlk, 256, 0, stream>>>(dst, deg, E);
    block_sums_kernel<<<nBlk256, 256, 0, stream>>>(deg, bsums, N);
    scan_bsums_kernel<<<1, 512, 0, stream>>>(bsums, nBlk256);
    scan_final_kernel<<<nBlk256, 256, 0, stream>>>(deg, bsums, rowptr, N);
    copy_kernel<<<nBlk256, 256, 0, stream>>>(rowptr, cursor, N);
    gcur_init_kernel<<<1, 256, 0, stream>>>(rowptr, gcur, nb, N);

    // 2-pass bucketed CSR fill
    bucketA_kernel<<<(E + 8191) / 8192, 256, 0, stream>>>(src, dst, gcur, stage, E);
    bucketB_kernel<<<nb8 * 16, 256, 0, stream>>>(stage, rowptr, cursor, eidx, nb, nb8, N);

    // weight fragments
    wf_prep_kernel<<<256, 256, 0, stream>>>(Wrel2, Wroot2, Wrel3, Wroot3, WF2, WF3);

    // layer 1 (Cin=1)
    gather1_kernel<<<(N + 255) / 256, 256, 0, stream>>>(x, rowptr, eidx, agg1, N);
    layer1_kernel<<<(N * 128 + 255) / 256, 256, 0, stream>>>(x, agg1, Wrel1, brel1, Wroot1,
                                                             g1, be1, m1, v1, hA, N);

    const int nwt     = (N + 31) / 32;
    const int convBlk = (nwt + 3) / 4;

    // layer 2
    gather_bf16_kernel<<<(N + 3) / 4, 256, 0, stream>>>(hA, rowptr, eidx, aggb, N);
    conv_mfma_kernel<1><<<convBlk, 256, 0, stream>>>((const short*)aggb, (const short*)hA,
                                                     (const short*)WF2, brel2, g2, be2, m2, v2,
                                                     hB, N);

    // layer 3
    gather_bf16_kernel<<<(N + 3) / 4, 256, 0, stream>>>(hB, rowptr, eidx, aggb, N);
    conv_mfma_kernel<0><<<convBlk, 256, 0, stream>>>((const short*)aggb, (const short*)hB,
                                                     (const short*)WF3, brel3, g3, be3, m3, v3,
                                                     hA, N);

    // pool + output
    pool_partial_kernel<<<(N + 511) / 512, 128, 0, stream>>>(hA, batch, gsums, gcnt, N);
    out_kernel<<<G, 128, 0, stream>>>(gsums, gcnt, Wout, bout, out);
}

// Round 3
// 448.433 us; speedup vs baseline: 2.9684x; 1.7704x over previous
//
#include <hip/hip_runtime.h>

typedef unsigned int uint;
typedef unsigned short ushort;

#define EPS 1e-5f
#define BSH 8        // bucket = 256 dst nodes
#define NBMAX 512
#define BCAP 10240   // LDS-cached bucket capacity (edges); fallback to global if exceeded

typedef __attribute__((ext_vector_type(8))) short short8;
typedef __attribute__((ext_vector_type(16))) float f32x16;

static __device__ __forceinline__ ushort f2b(float f) {
    uint u = __float_as_uint(f);
    u = (u + 0x7fffu + ((u >> 16) & 1u)) >> 16;
    return (ushort)u;
}
static __device__ __forceinline__ float blo(uint u) { return __uint_as_float(u << 16); }
static __device__ __forceinline__ float bhi(uint u) { return __uint_as_float(u & 0xffff0000u); }

// ---------------------------------------------------------------- CSR build
// A0: per-bucket edge counts (LDS hist, one global atomic per bucket per block)
__global__ __launch_bounds__(256) void bucket_count_kernel(const int* __restrict__ dst,
                                                           int* __restrict__ bcnt, int E, int NB) {
    __shared__ int lh[NBMAX];
    const int tid = threadIdx.x;
    for (int t = tid; t < NB; t += 256) lh[t] = 0;
    __syncthreads();
    const int base = blockIdx.x * 8192, end = min(base + 8192, E);
    for (int i = base + tid; i < end; i += 256) atomicAdd(&lh[dst[i] >> BSH], 1);
    __syncthreads();
    for (int t = tid; t < NB; t += 256) {
        int c = lh[t];
        if (c) atomicAdd(&bcnt[t], c);
    }
}

// A1: exclusive scan bcnt -> gcur (single block, 512 threads, NB<=512)
__global__ void scan_gcur_kernel(const int* __restrict__ bcnt, int* __restrict__ gcur, int nb) {
    int t = threadIdx.x;
    int orig = (t < nb) ? bcnt[t] : 0;
    int v = orig;
    int lane = t & 63, w = t >> 6;
#pragma unroll
    for (int d = 1; d < 64; d <<= 1) { int u = __shfl_up(v, d); if (lane >= d) v += u; }
    __shared__ int wsum[8];
    if (lane == 63) wsum[w] = v;
    __syncthreads();
    int off = 0;
    for (int i = 0; i < w; ++i) off += wsum[i];
    if (t < nb) gcur[t] = off + v - orig;   // exclusive
}

// A2: scatter edges into bucket-contiguous stage; packed 4B: src | (dst&255)<<17
__global__ __launch_bounds__(256) void bucket_scatter_kernel(const int* __restrict__ src,
                                                             const int* __restrict__ dst,
                                                             int* __restrict__ gcur,
                                                             uint* __restrict__ stage,
                                                             int E, int NB) {
    __shared__ int ldst[8192];
    __shared__ int lh[NBMAX];
    __shared__ int lbase[NBMAX];
    const int tid = threadIdx.x;
    const int base = blockIdx.x * 8192;
    const int len = min(base + 8192, E) - base;
    for (int t = tid; t < NB; t += 256) lh[t] = 0;
    for (int i = tid; i < len; i += 256) ldst[i] = dst[base + i];
    __syncthreads();
    for (int i = tid; i < len; i += 256) atomicAdd(&lh[ldst[i] >> BSH], 1);
    __syncthreads();
    for (int t = tid; t < NB; t += 256) {
        int c = lh[t];
        lbase[t] = c ? atomicAdd(&gcur[t], c) : 0;
        lh[t] = 0;
    }
    __syncthreads();
    for (int i = tid; i < len; i += 256) {
        int d = ldst[i];
        int b = d >> BSH;
        int pos = lbase[b] + atomicAdd(&lh[b], 1);
        stage[pos] = (uint)src[base + i] | ((uint)(d & 255) << 17);
    }
}

// B: per-bucket finalize: LDS hist -> scan -> rowptr + place via LDS cursors
__global__ __launch_bounds__(256) void bucket_final_kernel(const uint* __restrict__ stage,
                                                           const int* __restrict__ gcur,
                                                           int* __restrict__ rowptr,
                                                           int* __restrict__ eidx, int n) {
    __shared__ uint sbuf[BCAP];
    __shared__ int cnt[256];
    __shared__ int wsum[4];
    const int b = blockIdx.x, tid = threadIdx.x;
    const int r0 = b ? gcur[b - 1] : 0;
    const int r1 = gcur[b];
    const int len = r1 - r0;
    const bool inl = (len <= BCAP);
    cnt[tid] = 0;
    if (inl) for (int i = tid; i < len; i += 256) sbuf[i] = stage[r0 + i];
    __syncthreads();
    for (int i = tid; i < len; i += 256) {
        uint v = inl ? sbuf[i] : stage[r0 + i];
        atomicAdd(&cnt[v >> 17], 1);
    }
    __syncthreads();
    int orig = cnt[tid], v = orig;
    int lane = tid & 63, w = tid >> 6;
#pragma unroll
    for (int d2 = 1; d2 < 64; d2 <<= 1) { int u = __shfl_up(v, d2); if (lane >= d2) v += u; }
    if (lane == 63) wsum[w] = v;
    __syncthreads();
    int off = 0;
    for (int k = 0; k < w; ++k) off += wsum[k];
    const int excl = r0 + off + v - orig;   // absolute exclusive slot base
    const int d = (b << BSH) + tid;
    if (d <= n) rowptr[d] = excl;           // last bucket writes rowptr[n] = E
    __syncthreads();
    cnt[tid] = excl;
    __syncthreads();
    for (int i = tid; i < len; i += 256) {
        uint pv = inl ? sbuf[i] : stage[r0 + i];
        int slot = atomicAdd(&cnt[pv >> 17], 1);
        eidx[slot] = (int)(pv & 0x1FFFFu);
    }
}

// ---------------------------------------------------------------- layer 1 (Cin = 1)
__global__ void gather1_kernel(const float* __restrict__ x, const int* __restrict__ rowptr,
                               const int* __restrict__ eidx, float* __restrict__ agg1, int n) {
    int i = blockIdx.x * 256 + threadIdx.x;
    if (i >= n) return;
    float acc = 0.f;
    int e0 = rowptr[i], e1 = rowptr[i + 1];
    for (int e = e0; e < e1; ++e) acc += x[eidx[e]];
    agg1[i] = acc;
}

__global__ void layer1_kernel(const float* __restrict__ x, const float* __restrict__ agg1,
                              const float* __restrict__ Wrel, const float* __restrict__ brel,
                              const float* __restrict__ Wroot,
                              const float* __restrict__ gamma, const float* __restrict__ beta,
                              const float* __restrict__ mean, const float* __restrict__ var,
                              ushort* __restrict__ h1, int n) {
    int idx = blockIdx.x * 256 + threadIdx.x;
    int i = idx >> 7, c = idx & 127;
    if (i >= n) return;
    float s = gamma[c] * rsqrtf(var[c] + EPS);
    float t = beta[c] - mean[c] * s;
    float v = agg1[i] * Wrel[c] + brel[c] + x[i] * Wroot[c];
    v = v * s + t;
    h1[idx] = f2b(fmaxf(v, 0.f));
}

// ---------------------------------------------------------------- aggregation (bf16, H=128)
__global__ __launch_bounds__(256) void gather_bf16_kernel(const ushort* __restrict__ h,
                                                          const int* __restrict__ rowptr,
                                                          const int* __restrict__ eidx,
                                                          ushort* __restrict__ agg, int n) {
    int node = blockIdx.x * 4 + (threadIdx.x >> 6);
    if (node >= n) return;
    int lane = threadIdx.x & 63;
    const uint* hu = (const uint*)h;
    int e0 = rowptr[node], e1 = rowptr[node + 1];
    float a0 = 0.f, a1 = 0.f;
    int e = e0;
    for (; e + 4 <= e1; e += 4) {
        int s0 = eidx[e], s1 = eidx[e + 1], s2 = eidx[e + 2], s3 = eidx[e + 3];
        uint u0 = hu[s0 * 64 + lane];
        uint u1 = hu[s1 * 64 + lane];
        uint u2 = hu[s2 * 64 + lane];
        uint u3 = hu[s3 * 64 + lane];
        a0 += (blo(u0) + blo(u1)) + (blo(u2) + blo(u3));
        a1 += (bhi(u0) + bhi(u1)) + (bhi(u2) + bhi(u3));
    }
    for (; e < e1; ++e) {
        uint u = hu[eidx[e] * 64 + lane];
        a0 += blo(u);
        a1 += bhi(u);
    }
    uint o = (uint)f2b(a0) | ((uint)f2b(a1) << 16);
    ((uint*)agg)[node * 64 + lane] = o;
}

// ---------------------------------------------------------------- weight fragment prep
// WF layout: [half][kt 0..7][ct 0..3][lane 0..63][j 0..7]  (bf16)
// frag element = W_half[ct*32 + (lane&31)][kt*16 + (lane>>5)*8 + j]
__global__ void wf_prep_kernel(const float* __restrict__ W0, const float* __restrict__ W1,
                               const float* __restrict__ W2, const float* __restrict__ W3,
                               ushort* __restrict__ WF2, ushort* __restrict__ WF3) {
    int i = blockIdx.x * 256 + threadIdx.x;   // 65536 threads
    const float* Ws[4] = {W0, W1, W2, W3};
    int mat = i >> 14;
    int m = i & 16383;
    int j = m & 7, lane = (m >> 3) & 63, ct = (m >> 9) & 3, kt = (m >> 11) & 7;
    int row = ct * 32 + (lane & 31);
    int col = kt * 16 + ((lane >> 5) * 8) + j;
    float v = Ws[mat][row * 128 + col];
    ushort* dstp = (mat < 2) ? WF2 : WF3;
    dstp[(mat & 1) * 16384 + m] = f2b(v);
}

// ---------------------------------------------------------------- fused conv via MFMA
template <int RELU>
__global__ __launch_bounds__(256) void conv_mfma_kernel(
    const short* __restrict__ agg, const short* __restrict__ hin,
    const short* __restrict__ WF,
    const float* __restrict__ brel, const float* __restrict__ gamma,
    const float* __restrict__ beta, const float* __restrict__ mean,
    const float* __restrict__ var,
    ushort* __restrict__ hout, int n) {
    const int lane = threadIdx.x & 63;
    const int wt = blockIdx.x * 4 + (threadIdx.x >> 6);
    const int node0 = wt * 32;
    if (node0 >= n) return;
    const int rowA = node0 + (lane & 31);
    const int arow = (rowA < n) ? rowA : (n - 1);
    const int koff = (lane >> 5) * 8;

    f32x16 acc[4];
#pragma unroll
    for (int c = 0; c < 4; ++c) acc[c] = (f32x16)(0.0f);

#pragma unroll
    for (int half = 0; half < 2; ++half) {
        const short* A = (half ? hin : agg) + (size_t)arow * 128 + koff;
        const short* B0 = WF + half * 16384 + lane * 8;
#pragma unroll
        for (int kt = 0; kt < 8; ++kt) {
            short8 a = *(const short8*)(A + kt * 16);
            const short* Bp = B0 + kt * 2048;
#pragma unroll
            for (int ct = 0; ct < 4; ++ct) {
                short8 b = *(const short8*)(Bp + ct * 512);
                acc[ct] = __builtin_amdgcn_mfma_f32_32x32x16_bf16(a, b, acc[ct], 0, 0, 0);
            }
        }
    }

#pragma unroll
    for (int ct = 0; ct < 4; ++ct) {
        int c = ct * 32 + (lane & 31);
        float s = gamma[c] * rsqrtf(var[c] + EPS);
        float t = beta[c] - mean[c] * s + brel[c] * s;
#pragma unroll
        for (int r = 0; r < 16; ++r) {
            int row = (r & 3) + 8 * (r >> 2) + 4 * (lane >> 5);
            int node = node0 + row;
            if (node < n) {
                float v = acc[ct][r] * s + t;
                if (RELU) v = fmaxf(v, 0.f);
                hout[(size_t)node * 128 + c] = f2b(v);
            }
        }
    }
}

// ---------------------------------------------------------------- pooling (batch sorted)
// one wave per 64 contiguous nodes; lane = channel pair; run-length + atomic flush
__global__ __launch_bounds__(256) void pool_kernel(const ushort* __restrict__ h,
                                                   const int* __restrict__ batch,
                                                   float* __restrict__ gsums,
                                                   int* __restrict__ gcnt, int n) {
    const int wv = blockIdx.x * 4 + (threadIdx.x >> 6);
    const int lane = threadIdx.x & 63;
    const int base = wv * 64;
    if (base >= n) return;
    const int end = min(base + 64, n);
    const uint* hu = (const uint*)h;
    float a0 = 0.f, a1 = 0.f;
    int cur = batch[base], cl = 0;
    int i = base;
    for (; i + 4 <= end; i += 4) {
        int b3 = batch[i + 3];
        uint u0 = hu[(size_t)i * 64 + lane];
        uint u1 = hu[(size_t)(i + 1) * 64 + lane];
        uint u2 = hu[(size_t)(i + 2) * 64 + lane];
        uint u3 = hu[(size_t)(i + 3) * 64 + lane];
        if (b3 == cur) {   // sorted: b3==cur -> all four == cur
            a0 += (blo(u0) + blo(u1)) + (blo(u2) + blo(u3));
            a1 += (bhi(u0) + bhi(u1)) + (bhi(u2) + bhi(u3));
            cl += 4;
        } else {
            int bb[4] = {batch[i], batch[i + 1], batch[i + 2], b3};
            uint uu[4] = {u0, u1, u2, u3};
            for (int k = 0; k < 4; ++k) {
                if (bb[k] != cur) {
                    atomicAdd(&gsums[cur * 128 + lane * 2], a0);
                    atomicAdd(&gsums[cur * 128 + lane * 2 + 1], a1);
                    if (lane == 0) atomicAdd(&gcnt[cur], cl);
                    a0 = a1 = 0.f; cl = 0; cur = bb[k];
                }
                a0 += blo(uu[k]); a1 += bhi(uu[k]); cl++;
            }
        }
    }
    for (; i < end; ++i) {
        int g = batch[i];
        if (g != cur) {
            atomicAdd(&gsums[cur * 128 + lane * 2], a0);
            atomicAdd(&gsums[cur * 128 + lane * 2 + 1], a1);
            if (lane == 0) atomicAdd(&gcnt[cur], cl);
            a0 = a1 = 0.f; cl = 0; cur = g;
        }
        uint u = hu[(size_t)i * 64 + lane];
        a0 += blo(u); a1 += bhi(u); cl++;
    }
    atomicAdd(&gsums[cur * 128 + lane * 2], a0);
    atomicAdd(&gsums[cur * 128 + lane * 2 + 1], a1);
    if (lane == 0) atomicAdd(&gcnt[cur], cl);
}

__global__ void out_kernel(const float* __restrict__ sums, const int* __restrict__ cnt,
                           const float* __restrict__ Wout, const float* __restrict__ bout,
                           float* __restrict__ out) {
    int g = blockIdx.x, t = threadIdx.x;   // 128 threads
    float cn = fmaxf((float)cnt[g], 1.0f);
    float v = sums[g * 128 + t] / cn * Wout[t];
#pragma unroll
    for (int d = 32; d > 0; d >>= 1) v += __shfl_down(v, d);
    __shared__ float ws2[2];
    if ((t & 63) == 0) ws2[t >> 6] = v;
    __syncthreads();
    if (t == 0) out[g] = ws2[0] + ws2[1] + bout[0];
}

// ---------------------------------------------------------------- launch
extern "C" void kernel_launch(void* const* d_in, const int* in_sizes, int n_in,
                              void* d_out, int out_size, void* d_ws, size_t ws_size,
                              hipStream_t stream) {
    const int N = in_sizes[0];            // 100000 (< 2^17, required by stage packing)
    const int E = in_sizes[1] / 2;
    const int G = 64;

    const float* x     = (const float*)d_in[0];
    const int*   ei    = (const int*)d_in[1];
    const int*   batch = (const int*)d_in[2];
    const int*   src   = ei;
    const int*   dst   = ei + E;

    const float* Wrel1 = (const float*)d_in[3];
    const float* brel1 = (const float*)d_in[4];
    const float* Wroot1= (const float*)d_in[5];
    const float* g1    = (const float*)d_in[6];
    const float* be1   = (const float*)d_in[7];
    const float* m1    = (const float*)d_in[8];
    const float* v1    = (const float*)d_in[9];
    const float* Wrel2 = (const float*)d_in[10];
    const float* brel2 = (const float*)d_in[11];
    const float* Wroot2= (const float*)d_in[12];
    const float* g2    = (const float*)d_in[13];
    const float* be2   = (const float*)d_in[14];
    const float* m2    = (const float*)d_in[15];
    const float* v2    = (const float*)d_in[16];
    const float* Wrel3 = (const float*)d_in[17];
    const float* brel3 = (const float*)d_in[18];
    const float* Wroot3= (const float*)d_in[19];
    const float* g3    = (const float*)d_in[20];
    const float* be3   = (const float*)d_in[21];
    const float* m3    = (const float*)d_in[22];
    const float* v3    = (const float*)d_in[23];
    const float* Wout  = (const float*)d_in[24];
    const float* bout  = (const float*)d_in[25];

    float* out = (float*)d_out;

    // workspace carve (512B aligned)
    char* w = (char*)d_ws;
    auto alloc = [&](size_t bytes) { char* p = w; w += (bytes + 511) & ~(size_t)511; return p; };
    int*    rowptr = (int*)alloc((size_t)(N + 1) * 4);
    int*    bcnt   = (int*)alloc(NBMAX * 4);
    int*    gcur   = (int*)alloc(NBMAX * 4);
    uint*   stage  = (uint*)alloc((size_t)E * 4);
    int*    eidx   = (int*)alloc((size_t)E * 4);
    float*  agg1   = (float*)alloc((size_t)N * 4);
    ushort* hA     = (ushort*)alloc((size_t)N * 128 * 2);
    ushort* hB     = (ushort*)alloc((size_t)N * 128 * 2);
    ushort* aggb   = (ushort*)alloc((size_t)N * 128 * 2);
    ushort* WF2    = (ushort*)alloc(32768 * 2);
    ushort* WF3    = (ushort*)alloc(32768 * 2);
    float*  gsums  = (float*)alloc((size_t)G * 128 * 4);
    int*    gcnt   = (int*)alloc((size_t)G * 4);

    const int NB   = (N >> BSH) + 1;      // 391 buckets of 256 dsts
    const int eBlk = (E + 8191) / 8192;

    hipMemsetAsync(bcnt, 0, NBMAX * 4, stream);
    hipMemsetAsync(gsums, 0, (size_t)G * 128 * 4, stream);
    hipMemsetAsync(gcnt, 0, (size_t)G * 4, stream);

    // CSR build: bucket count -> scan -> scatter -> per-bucket finalize
    bucket_count_kernel<<<eBlk, 256, 0, stream>>>(dst, bcnt, E, NB);
    scan_gcur_kernel<<<1, 512, 0, stream>>>(bcnt, gcur, NB);
    bucket_scatter_kernel<<<eBlk, 256, 0, stream>>>(src, dst, gcur, stage, E, NB);
    bucket_final_kernel<<<NB, 256, 0, stream>>>(stage, gcur, rowptr, eidx, N);

    // weight fragments
    wf_prep_kernel<<<256, 256, 0, stream>>>(Wrel2, Wroot2, Wrel3, Wroot3, WF2, WF3);

    // layer 1 (Cin=1)
    gather1_kernel<<<(N + 255) / 256, 256, 0, stream>>>(x, rowptr, eidx, agg1, N);
    layer1_kernel<<<(N * 128 + 255) / 256, 256, 0, stream>>>(x, agg1, Wrel1, brel1, Wroot1,
                                                             g1, be1, m1, v1, hA, N);

    const int nwt     = (N + 31) / 32;
    const int convBlk = (nwt + 3) / 4;

    // layer 2
    gather_bf16_kernel<<<(N + 3) / 4, 256, 0, stream>>>(hA, rowptr, eidx, aggb, N);
    conv_mfma_kernel<1><<<convBlk, 256, 0, stream>>>((const short*)aggb, (const short*)hA,
                                                     (const short*)WF2, brel2, g2, be2, m2, v2,
                                                     hB, N);

    // layer 3
    gather_bf16_kernel<<<(N + 3) / 4, 256, 0, stream>>>(hB, rowptr, eidx, aggb, N);
    conv_mfma_kernel<0><<<convBlk, 256, 0, stream>>>((const short*)aggb, (const short*)hB,
                                                     (const short*)WF3, brel3, g3, be3, m3, v3,
                                                     hA, N);

    // pool + output
    pool_kernel<<<(N + 255) / 256, 256, 0, stream>>>(hA, batch, gsums, gcnt, N);
    out_kernel<<<G, 128, 0, stream>>>(gsums, gcnt, Wout, bout, out);
}

// Round 4
// 422.425 us; speedup vs baseline: 3.1511x; 1.0616x over previous
//
#include <hip/hip_runtime.h>

typedef unsigned int uint;
typedef unsigned short ushort;

#define EPS 1e-5f
#define BSH 8        // bucket = 256 dst nodes
#define NBMAX 512
#define BCAP 10240   // LDS-cached bucket capacity (edges); fallback to global if exceeded

typedef __attribute__((ext_vector_type(8))) short short8;
typedef __attribute__((ext_vector_type(16))) float f32x16;
typedef __attribute__((ext_vector_type(2))) _Float16 half2v;
typedef __attribute__((ext_vector_type(8))) _Float16 f16x8;

static __device__ __forceinline__ ushort f2h(float f) {
    return __builtin_bit_cast(ushort, (_Float16)f);
}

// ---------------------------------------------------------------- CSR build
// A0: per-bucket edge counts (LDS hist, one global atomic per bucket per block)
__global__ __launch_bounds__(256) void bucket_count_kernel(const int* __restrict__ dst,
                                                           int* __restrict__ bcnt, int E, int NB) {
    __shared__ int lh[NBMAX];
    const int tid = threadIdx.x;
    for (int t = tid; t < NB; t += 256) lh[t] = 0;
    __syncthreads();
    const int base = blockIdx.x * 8192, end = min(base + 8192, E);
    for (int i = base + tid; i < end; i += 256) atomicAdd(&lh[dst[i] >> BSH], 1);
    __syncthreads();
    for (int t = tid; t < NB; t += 256) {
        int c = lh[t];
        if (c) atomicAdd(&bcnt[t], c);
    }
}

// A1: exclusive scan bcnt -> gcur (single block, 512 threads, NB<=512)
__global__ void scan_gcur_kernel(const int* __restrict__ bcnt, int* __restrict__ gcur, int nb) {
    int t = threadIdx.x;
    int orig = (t < nb) ? bcnt[t] : 0;
    int v = orig;
    int lane = t & 63, w = t >> 6;
#pragma unroll
    for (int d = 1; d < 64; d <<= 1) { int u = __shfl_up(v, d); if (lane >= d) v += u; }
    __shared__ int wsum[8];
    if (lane == 63) wsum[w] = v;
    __syncthreads();
    int off = 0;
    for (int i = 0; i < w; ++i) off += wsum[i];
    if (t < nb) gcur[t] = off + v - orig;   // exclusive
}

// A2: scatter edges into bucket-contiguous stage; packed 4B: src | (dst&255)<<17
__global__ __launch_bounds__(256) void bucket_scatter_kernel(const int* __restrict__ src,
                                                             const int* __restrict__ dst,
                                                             int* __restrict__ gcur,
                                                             uint* __restrict__ stage,
                                                             int E, int NB) {
    __shared__ int ldst[8192];
    __shared__ int lh[NBMAX];
    __shared__ int lbase[NBMAX];
    const int tid = threadIdx.x;
    const int base = blockIdx.x * 8192;
    const int len = min(base + 8192, E) - base;
    for (int t = tid; t < NB; t += 256) lh[t] = 0;
    for (int i = tid; i < len; i += 256) ldst[i] = dst[base + i];
    __syncthreads();
    for (int i = tid; i < len; i += 256) atomicAdd(&lh[ldst[i] >> BSH], 1);
    __syncthreads();
    for (int t = tid; t < NB; t += 256) {
        int c = lh[t];
        lbase[t] = c ? atomicAdd(&gcur[t], c) : 0;
        lh[t] = 0;
    }
    __syncthreads();
    for (int i = tid; i < len; i += 256) {
        int d = ldst[i];
        int b = d >> BSH;
        int pos = lbase[b] + atomicAdd(&lh[b], 1);
        stage[pos] = (uint)src[base + i] | ((uint)(d & 255) << 17);
    }
}

// B: per-bucket finalize: LDS hist -> scan -> rowptr + place via LDS cursors
__global__ __launch_bounds__(256) void bucket_final_kernel(const uint* __restrict__ stage,
                                                           const int* __restrict__ gcur,
                                                           int* __restrict__ rowptr,
                                                           int* __restrict__ eidx, int n) {
    __shared__ uint sbuf[BCAP];
    __shared__ int cnt[256];
    __shared__ int wsum[4];
    const int b = blockIdx.x, tid = threadIdx.x;
    const int r0 = b ? gcur[b - 1] : 0;
    const int r1 = gcur[b];
    const int len = r1 - r0;
    const bool inl = (len <= BCAP);
    cnt[tid] = 0;
    if (inl) for (int i = tid; i < len; i += 256) sbuf[i] = stage[r0 + i];
    __syncthreads();
    for (int i = tid; i < len; i += 256) {
        uint v = inl ? sbuf[i] : stage[r0 + i];
        atomicAdd(&cnt[v >> 17], 1);
    }
    __syncthreads();
    int orig = cnt[tid], v = orig;
    int lane = tid & 63, w = tid >> 6;
#pragma unroll
    for (int d2 = 1; d2 < 64; d2 <<= 1) { int u = __shfl_up(v, d2); if (lane >= d2) v += u; }
    if (lane == 63) wsum[w] = v;
    __syncthreads();
    int off = 0;
    for (int k = 0; k < w; ++k) off += wsum[k];
    const int excl = r0 + off + v - orig;   // absolute exclusive slot base
    const int d = (b << BSH) + tid;
    if (d <= n) rowptr[d] = excl;           // last bucket writes rowptr[n] = E
    __syncthreads();
    cnt[tid] = excl;
    __syncthreads();
    for (int i = tid; i < len; i += 256) {
        uint pv = inl ? sbuf[i] : stage[r0 + i];
        int slot = atomicAdd(&cnt[pv >> 17], 1);
        eidx[slot] = (int)(pv & 0x1FFFFu);
    }
}

// ---------------------------------------------------------------- layer 1 (Cin = 1)
__global__ void gather1_kernel(const float* __restrict__ x, const int* __restrict__ rowptr,
                               const int* __restrict__ eidx, float* __restrict__ agg1, int n) {
    int i = blockIdx.x * 256 + threadIdx.x;
    if (i >= n) return;
    float acc = 0.f;
    int e0 = rowptr[i], e1 = rowptr[i + 1];
    for (int e = e0; e < e1; ++e) acc += x[eidx[e]];
    agg1[i] = acc;
}

__global__ void layer1_kernel(const float* __restrict__ x, const float* __restrict__ agg1,
                              const float* __restrict__ Wrel, const float* __restrict__ brel,
                              const float* __restrict__ Wroot,
                              const float* __restrict__ gamma, const float* __restrict__ beta,
                              const float* __restrict__ mean, const float* __restrict__ var,
                              ushort* __restrict__ h1, int n) {
    int idx = blockIdx.x * 256 + threadIdx.x;
    int i = idx >> 7, c = idx & 127;
    if (i >= n) return;
    float s = gamma[c] * rsqrtf(var[c] + EPS);
    float t = beta[c] - mean[c] * s;
    float v = agg1[i] * Wrel[c] + brel[c] + x[i] * Wroot[c];
    v = v * s + t;
    h1[idx] = f2h(fmaxf(v, 0.f));
}

// ---------------------------------------------------------------- aggregation (f16, H=128)
// one node per wave; lane covers 8B (4 channels) of edge e + (lane>>5);
// srcs preloaded 64-wide and broadcast via shfl; packed v_pk_add_f16 accumulate.
__global__ __launch_bounds__(256) void gather_f16_kernel(const ushort* __restrict__ h,
                                                         const int* __restrict__ rowptr,
                                                         const int* __restrict__ eidx,
                                                         ushort* __restrict__ agg, int n) {
    const int node = blockIdx.x * 4 + (threadIdx.x >> 6);
    if (node >= n) return;
    const int lane = threadIdx.x & 63;
    const int hf = lane >> 5;       // which edge of the pair
    const int cp = lane & 31;       // uint2 slot within the 256B row
    const uint2* hq = (const uint2*)h;   // 32 uint2 per row
    const int e0 = rowptr[node];
    const int len = rowptr[node + 1] - e0;

    half2v a0 = (half2v)0, a1 = (half2v)0;

    for (int base = 0; base < len; base += 64) {
        const int cnt = min(len - base, 64);
        int msrc = (lane < cnt) ? eidx[e0 + base + lane] : 0;
        int k = 0;
        for (; k + 16 <= cnt; k += 16) {
#pragma unroll
            for (int q = 0; q < 8; ++q) {
                int src = __shfl(msrc, k + q * 2 + hf);
                uint2 u = hq[(size_t)src * 32 + cp];
                a0 += __builtin_bit_cast(half2v, u.x);
                a1 += __builtin_bit_cast(half2v, u.y);
            }
        }
        for (; k < cnt; k += 2) {
            int idx = k + hf;
            int src = __shfl(msrc, min(idx, cnt - 1));
            if (idx < cnt) {
                uint2 u = hq[(size_t)src * 32 + cp];
                a0 += __builtin_bit_cast(half2v, u.x);
                a1 += __builtin_bit_cast(half2v, u.y);
            }
        }
    }
    // combine the two edge-parity halves
    uint t0 = __shfl_xor(__builtin_bit_cast(uint, a0), 32);
    uint t1 = __shfl_xor(__builtin_bit_cast(uint, a1), 32);
    a0 += __builtin_bit_cast(half2v, t0);
    a1 += __builtin_bit_cast(half2v, t1);
    if (hf == 0) {
        uint2 o;
        o.x = __builtin_bit_cast(uint, a0);
        o.y = __builtin_bit_cast(uint, a1);
        ((uint2*)agg)[(size_t)node * 32 + cp] = o;
    }
}

// ---------------------------------------------------------------- weight fragment prep
// WF layout: [half][kt 0..7][ct 0..3][lane 0..63][j 0..7]  (f16)
// frag element = W_half[ct*32 + (lane&31)][kt*16 + (lane>>5)*8 + j]
__global__ void wf_prep_kernel(const float* __restrict__ W0, const float* __restrict__ W1,
                               const float* __restrict__ W2, const float* __restrict__ W3,
                               ushort* __restrict__ WF2, ushort* __restrict__ WF3) {
    int i = blockIdx.x * 256 + threadIdx.x;   // 65536 threads
    const float* Ws[4] = {W0, W1, W2, W3};
    int mat = i >> 14;
    int m = i & 16383;
    int j = m & 7, lane = (m >> 3) & 63, ct = (m >> 9) & 3, kt = (m >> 11) & 7;
    int row = ct * 32 + (lane & 31);
    int col = kt * 16 + ((lane >> 5) * 8) + j;
    float v = Ws[mat][row * 128 + col];
    ushort* dstp = (mat < 2) ? WF2 : WF3;
    dstp[(mat & 1) * 16384 + m] = f2h(v);
}

// ---------------------------------------------------------------- fused conv via MFMA (f16)
template <int RELU>
__global__ __launch_bounds__(256) void conv_mfma_kernel(
    const short* __restrict__ agg, const short* __restrict__ hin,
    const short* __restrict__ WF,
    const float* __restrict__ brel, const float* __restrict__ gamma,
    const float* __restrict__ beta, const float* __restrict__ mean,
    const float* __restrict__ var,
    ushort* __restrict__ hout, int n) {
    const int lane = threadIdx.x & 63;
    const int wt = blockIdx.x * 4 + (threadIdx.x >> 6);
    const int node0 = wt * 32;
    if (node0 >= n) return;
    const int rowA = node0 + (lane & 31);
    const int arow = (rowA < n) ? rowA : (n - 1);
    const int koff = (lane >> 5) * 8;

    f32x16 acc[4];
#pragma unroll
    for (int c = 0; c < 4; ++c) acc[c] = (f32x16)(0.0f);

#pragma unroll
    for (int half = 0; half < 2; ++half) {
        const short* A = (half ? hin : agg) + (size_t)arow * 128 + koff;
        const short* B0 = WF + half * 16384 + lane * 8;
#pragma unroll
        for (int kt = 0; kt < 8; ++kt) {
            f16x8 a = __builtin_bit_cast(f16x8, *(const short8*)(A + kt * 16));
            const short* Bp = B0 + kt * 2048;
#pragma unroll
            for (int ct = 0; ct < 4; ++ct) {
                f16x8 b = __builtin_bit_cast(f16x8, *(const short8*)(Bp + ct * 512));
                acc[ct] = __builtin_amdgcn_mfma_f32_32x32x16_f16(a, b, acc[ct], 0, 0, 0);
            }
        }
    }

#pragma unroll
    for (int ct = 0; ct < 4; ++ct) {
        int c = ct * 32 + (lane & 31);
        float s = gamma[c] * rsqrtf(var[c] + EPS);
        float t = beta[c] - mean[c] * s + brel[c] * s;
#pragma unroll
        for (int r = 0; r < 16; ++r) {
            int row = (r & 3) + 8 * (r >> 2) + 4 * (lane >> 5);
            int node = node0 + row;
            if (node < n) {
                float v = acc[ct][r] * s + t;
                if (RELU) v = fmaxf(v, 0.f);
                hout[(size_t)node * 128 + c] = f2h(v);
            }
        }
    }
}

// ---------------------------------------------------------------- pooling (batch sorted)
// fold W_out dot into the scan: per wave, per-graph scalar accumulator
__global__ __launch_bounds__(256) void pool_kernel(const ushort* __restrict__ h,
                                                   const int* __restrict__ batch,
                                                   const float* __restrict__ Wout,
                                                   float* __restrict__ gscal,
                                                   int* __restrict__ gcnt, int n) {
    const int wv = blockIdx.x * 4 + (threadIdx.x >> 6);
    const int lane = threadIdx.x & 63;
    const int base = wv * 64;
    if (base >= n) return;
    const int end = min(base + 64, n);
    const uint* hu = (const uint*)h;
    const float w0 = Wout[lane * 2], w1 = Wout[lane * 2 + 1];
    float s = 0.f;
    int cur = batch[base], cl = 0;

    auto accum = [&](uint u) {
        half2v hv = __builtin_bit_cast(half2v, u);
        s += (float)hv[0] * w0 + (float)hv[1] * w1;
        cl++;
    };
    auto flush = [&](int g) {
        float r = s;
#pragma unroll
        for (int d = 1; d < 64; d <<= 1) r += __shfl_xor(r, d);
        if (lane == 0) { atomicAdd(&gscal[g], r); atomicAdd(&gcnt[g], cl); }
        s = 0.f; cl = 0;
    };

    int i = base;
    for (; i + 4 <= end; i += 4) {
        int b3 = batch[i + 3];
        uint u0 = hu[(size_t)i * 64 + lane];
        uint u1 = hu[(size_t)(i + 1) * 64 + lane];
        uint u2 = hu[(size_t)(i + 2) * 64 + lane];
        uint u3 = hu[(size_t)(i + 3) * 64 + lane];
        if (b3 == cur) {
            accum(u0); accum(u1); accum(u2); accum(u3);
        } else {
            int bb[4] = {batch[i], batch[i + 1], batch[i + 2], b3};
            uint uu[4] = {u0, u1, u2, u3};
            for (int k = 0; k < 4; ++k) {
                if (bb[k] != cur) { flush(cur); cur = bb[k]; }
                accum(uu[k]);
            }
        }
    }
    for (; i < end; ++i) {
        int g = batch[i];
        if (g != cur) { flush(cur); cur = g; }
        accum(hu[(size_t)i * 64 + lane]);
    }
    flush(cur);
}

__global__ void out_kernel(const float* __restrict__ gscal, const int* __restrict__ gcnt,
                           const float* __restrict__ bout, float* __restrict__ out, int G) {
    int g = threadIdx.x;
    if (g < G) out[g] = gscal[g] / fmaxf((float)gcnt[g], 1.0f) + bout[0];
}

// ---------------------------------------------------------------- launch
extern "C" void kernel_launch(void* const* d_in, const int* in_sizes, int n_in,
                              void* d_out, int out_size, void* d_ws, size_t ws_size,
                              hipStream_t stream) {
    const int N = in_sizes[0];            // 100000 (< 2^17, required by stage packing)
    const int E = in_sizes[1] / 2;
    const int G = 64;

    const float* x     = (const float*)d_in[0];
    const int*   ei    = (const int*)d_in[1];
    const int*   batch = (const int*)d_in[2];
    const int*   src   = ei;
    const int*   dst   = ei + E;

    const float* Wrel1 = (const float*)d_in[3];
    const float* brel1 = (const float*)d_in[4];
    const float* Wroot1= (const float*)d_in[5];
    const float* g1    = (const float*)d_in[6];
    const float* be1   = (const float*)d_in[7];
    const float* m1    = (const float*)d_in[8];
    const float* v1    = (const float*)d_in[9];
    const float* Wrel2 = (const float*)d_in[10];
    const float* brel2 = (const float*)d_in[11];
    const float* Wroot2= (const float*)d_in[12];
    const float* g2    = (const float*)d_in[13];
    const float* be2   = (const float*)d_in[14];
    const float* m2    = (const float*)d_in[15];
    const float* v2    = (const float*)d_in[16];
    const float* Wrel3 = (const float*)d_in[17];
    const float* brel3 = (const float*)d_in[18];
    const float* Wroot3= (const float*)d_in[19];
    const float* g3    = (const float*)d_in[20];
    const float* be3   = (const float*)d_in[21];
    const float* m3    = (const float*)d_in[22];
    const float* v3    = (const float*)d_in[23];
    const float* Wout  = (const float*)d_in[24];
    const float* bout  = (const float*)d_in[25];

    float* out = (float*)d_out;

    // workspace carve (512B aligned)
    char* w = (char*)d_ws;
    auto alloc = [&](size_t bytes) { char* p = w; w += (bytes + 511) & ~(size_t)511; return p; };
    int*    rowptr = (int*)alloc((size_t)(N + 1) * 4);
    int*    bcnt   = (int*)alloc(NBMAX * 4);
    int*    gcur   = (int*)alloc(NBMAX * 4);
    uint*   stage  = (uint*)alloc((size_t)E * 4);
    int*    eidx   = (int*)alloc((size_t)E * 4);
    float*  agg1   = (float*)alloc((size_t)N * 4);
    ushort* hA     = (ushort*)alloc((size_t)N * 128 * 2);
    ushort* hB     = (ushort*)alloc((size_t)N * 128 * 2);
    ushort* aggb   = (ushort*)alloc((size_t)N * 128 * 2);
    ushort* WF2    = (ushort*)alloc(32768 * 2);
    ushort* WF3    = (ushort*)alloc(32768 * 2);
    float*  gscal  = (float*)alloc((size_t)G * 4);
    int*    gcnt   = (int*)alloc((size_t)G * 4);

    const int NB   = (N >> BSH) + 1;      // 391 buckets of 256 dsts
    const int eBlk = (E + 8191) / 8192;

    hipMemsetAsync(bcnt, 0, NBMAX * 4, stream);
    hipMemsetAsync(gscal, 0, (size_t)G * 4, stream);
    hipMemsetAsync(gcnt, 0, (size_t)G * 4, stream);

    // CSR build: bucket count -> scan -> scatter -> per-bucket finalize
    bucket_count_kernel<<<eBlk, 256, 0, stream>>>(dst, bcnt, E, NB);
    scan_gcur_kernel<<<1, 512, 0, stream>>>(bcnt, gcur, NB);
    bucket_scatter_kernel<<<eBlk, 256, 0, stream>>>(src, dst, gcur, stage, E, NB);
    bucket_final_kernel<<<NB, 256, 0, stream>>>(stage, gcur, rowptr, eidx, N);

    // weight fragments
    wf_prep_kernel<<<256, 256, 0, stream>>>(Wrel2, Wroot2, Wrel3, Wroot3, WF2, WF3);

    // layer 1 (Cin=1)
    gather1_kernel<<<(N + 255) / 256, 256, 0, stream>>>(x, rowptr, eidx, agg1, N);
    layer1_kernel<<<(N * 128 + 255) / 256, 256, 0, stream>>>(x, agg1, Wrel1, brel1, Wroot1,
                                                             g1, be1, m1, v1, hA, N);

    const int nwt     = (N + 31) / 32;
    const int convBlk = (nwt + 3) / 4;

    // layer 2
    gather_f16_kernel<<<(N + 3) / 4, 256, 0, stream>>>(hA, rowptr, eidx, aggb, N);
    conv_mfma_kernel<1><<<convBlk, 256, 0, stream>>>((const short*)aggb, (const short*)hA,
                                                     (const short*)WF2, brel2, g2, be2, m2, v2,
                                                     hB, N);

    // layer 3
    gather_f16_kernel<<<(N + 3) / 4, 256, 0, stream>>>(hB, rowptr, eidx, aggb, N);
    conv_mfma_kernel<0><<<convBlk, 256, 0, stream>>>((const short*)aggb, (const short*)hB,
                                                     (const short*)WF3, brel3, g3, be3, m3, v3,
                                                     hA, N);

    // pool + output
    pool_kernel<<<(N + 255) / 256, 256, 0, stream>>>(hA, batch, Wout, gscal, gcnt, N);
    out_kernel<<<1, 64, 0, stream>>>(gscal, gcnt, bout, out, G);
}

// Round 5
// 388.768 us; speedup vs baseline: 3.4240x; 1.0866x over previous
//
#include <hip/hip_runtime.h>

typedef unsigned int uint;
typedef unsigned short ushort;

#define EPS 1e-5f
#define BSH 8        // bucket = 256 dst nodes
#define NBMAX 512
#define BCAP 10240   // LDS-cached bucket capacity (edges); fallback to global if exceeded

typedef __attribute__((ext_vector_type(8))) short short8;
typedef __attribute__((ext_vector_type(16))) float f32x16;
typedef __attribute__((ext_vector_type(2))) _Float16 half2v;
typedef __attribute__((ext_vector_type(8))) _Float16 f16x8;

static __device__ __forceinline__ ushort f2h(float f) {
    return __builtin_bit_cast(ushort, (_Float16)f);
}
static __device__ __forceinline__ half2v u2h(uint u) {
    return __builtin_bit_cast(half2v, u);
}

// ---------------------------------------------------------------- CSR build
// A0: per-bucket edge counts (LDS hist, one global atomic per bucket per block)
__global__ __launch_bounds__(256) void bucket_count_kernel(const int* __restrict__ dst,
                                                           int* __restrict__ bcnt, int E, int NB) {
    __shared__ int lh[NBMAX];
    const int tid = threadIdx.x;
    for (int t = tid; t < NB; t += 256) lh[t] = 0;
    __syncthreads();
    const int base = blockIdx.x * 8192, end = min(base + 8192, E);
    for (int i = base + tid; i < end; i += 256) atomicAdd(&lh[dst[i] >> BSH], 1);
    __syncthreads();
    for (int t = tid; t < NB; t += 256) {
        int c = lh[t];
        if (c) atomicAdd(&bcnt[t], c);
    }
}

// A1: exclusive scan bcnt -> gcur (single block, 512 threads, NB<=512)
__global__ void scan_gcur_kernel(const int* __restrict__ bcnt, int* __restrict__ gcur, int nb) {
    int t = threadIdx.x;
    int orig = (t < nb) ? bcnt[t] : 0;
    int v = orig;
    int lane = t & 63, w = t >> 6;
#pragma unroll
    for (int d = 1; d < 64; d <<= 1) { int u = __shfl_up(v, d); if (lane >= d) v += u; }
    __shared__ int wsum[8];
    if (lane == 63) wsum[w] = v;
    __syncthreads();
    int off = 0;
    for (int i = 0; i < w; ++i) off += wsum[i];
    if (t < nb) gcur[t] = off + v - orig;   // exclusive
}

// A2: scatter edges into bucket-contiguous stage; packed 4B: src | (dst&255)<<17
__global__ __launch_bounds__(256) void bucket_scatter_kernel(const int* __restrict__ src,
                                                             const int* __restrict__ dst,
                                                             int* __restrict__ gcur,
                                                             uint* __restrict__ stage,
                                                             int E, int NB) {
    __shared__ int ldst[8192];
    __shared__ int lh[NBMAX];
    __shared__ int lbase[NBMAX];
    const int tid = threadIdx.x;
    const int base = blockIdx.x * 8192;
    const int len = min(base + 8192, E) - base;
    for (int t = tid; t < NB; t += 256) lh[t] = 0;
    for (int i = tid; i < len; i += 256) ldst[i] = dst[base + i];
    __syncthreads();
    for (int i = tid; i < len; i += 256) atomicAdd(&lh[ldst[i] >> BSH], 1);
    __syncthreads();
    for (int t = tid; t < NB; t += 256) {
        int c = lh[t];
        lbase[t] = c ? atomicAdd(&gcur[t], c) : 0;
        lh[t] = 0;
    }
    __syncthreads();
    for (int i = tid; i < len; i += 256) {
        int d = ldst[i];
        int b = d >> BSH;
        int pos = lbase[b] + atomicAdd(&lh[b], 1);
        stage[pos] = (uint)src[base + i] | ((uint)(d & 255) << 17);
    }
}

// B: per-bucket finalize: LDS hist -> scan -> rowptr + place via LDS cursors
__global__ __launch_bounds__(256) void bucket_final_kernel(const uint* __restrict__ stage,
                                                           const int* __restrict__ gcur,
                                                           int* __restrict__ rowptr,
                                                           int* __restrict__ eidx, int n) {
    __shared__ uint sbuf[BCAP];
    __shared__ int cnt[256];
    __shared__ int wsum[4];
    const int b = blockIdx.x, tid = threadIdx.x;
    const int r0 = b ? gcur[b - 1] : 0;
    const int r1 = gcur[b];
    const int len = r1 - r0;
    const bool inl = (len <= BCAP);
    cnt[tid] = 0;
    if (inl) for (int i = tid; i < len; i += 256) sbuf[i] = stage[r0 + i];
    __syncthreads();
    for (int i = tid; i < len; i += 256) {
        uint v = inl ? sbuf[i] : stage[r0 + i];
        atomicAdd(&cnt[v >> 17], 1);
    }
    __syncthreads();
    int orig = cnt[tid], v = orig;
    int lane = tid & 63, w = tid >> 6;
#pragma unroll
    for (int d2 = 1; d2 < 64; d2 <<= 1) { int u = __shfl_up(v, d2); if (lane >= d2) v += u; }
    if (lane == 63) wsum[w] = v;
    __syncthreads();
    int off = 0;
    for (int k = 0; k < w; ++k) off += wsum[k];
    const int excl = r0 + off + v - orig;   // absolute exclusive slot base
    const int d = (b << BSH) + tid;
    if (d <= n) rowptr[d] = excl;           // last bucket writes rowptr[n] = E
    __syncthreads();
    cnt[tid] = excl;
    __syncthreads();
    for (int i = tid; i < len; i += 256) {
        uint pv = inl ? sbuf[i] : stage[r0 + i];
        int slot = atomicAdd(&cnt[pv >> 17], 1);
        eidx[slot] = (int)(pv & 0x1FFFFu);
    }
}

// ---------------------------------------------------------------- layer 1 fused (Cin = 1)
// 16-lane group per node: parallel edge loads + shfl reduce, BN prefolded, 16B row writes
__global__ __launch_bounds__(256) void layer1_fused_kernel(
    const float* __restrict__ x, const int* __restrict__ rowptr, const int* __restrict__ eidx,
    const float* __restrict__ Wrel, const float* __restrict__ brel,
    const float* __restrict__ Wroot, const float* __restrict__ gamma,
    const float* __restrict__ beta, const float* __restrict__ mean,
    const float* __restrict__ var, ushort* __restrict__ h1, int n) {
    __shared__ float A[128], B[128], C[128];
    const int tid = threadIdx.x;
    if (tid < 128) {
        float sc = gamma[tid] * rsqrtf(var[tid] + EPS);
        A[tid] = Wrel[tid] * sc;
        B[tid] = Wroot[tid] * sc;
        C[tid] = beta[tid] + (brel[tid] - mean[tid]) * sc;
    }
    __syncthreads();
    const int g16 = tid >> 4;
    const int l16 = tid & 15;
    const int node = blockIdx.x * 16 + g16;
    if (node >= n) return;
    const int e0 = rowptr[node], e1 = rowptr[node + 1];
    float acc = 0.f;
    for (int e = e0 + l16; e < e1; e += 16) acc += x[eidx[e]];
#pragma unroll
    for (int d = 1; d < 16; d <<= 1) acc += __shfl_xor(acc, d);
    const float xi = x[node];
    uint4 o;
    ushort* op = (ushort*)&o;
#pragma unroll
    for (int j = 0; j < 8; ++j) {
        int c = l16 * 8 + j;
        op[j] = f2h(fmaxf(acc * A[c] + xi * B[c] + C[c], 0.f));
    }
    *((uint4*)(h1 + (size_t)node * 128) + l16) = o;
}

// ---------------------------------------------------------------- aggregation (f16, H=128)
// one node per wave; 16 lanes per edge (uint4 = 16B each); srcs broadcast via shfl;
// 8-deep load unroll (128B in flight per lane); packed v_pk_add_f16 accumulate.
__global__ __launch_bounds__(256) void gather_f16_kernel(const ushort* __restrict__ h,
                                                         const int* __restrict__ rowptr,
                                                         const int* __restrict__ eidx,
                                                         ushort* __restrict__ agg, int n) {
    const int node = blockIdx.x * 4 + (threadIdx.x >> 6);
    if (node >= n) return;
    const int lane = threadIdx.x & 63;
    const int g = lane >> 4;        // edge-group 0..3
    const int c16 = lane & 15;      // 16B slot within 256B row
    const uint4* hq = (const uint4*)h;   // 16 uint4 per row
    const int e0 = rowptr[node];
    const int len = rowptr[node + 1] - e0;

    half2v a0 = (half2v)0, a1 = (half2v)0, a2 = (half2v)0, a3 = (half2v)0;

    for (int base = 0; base < len; base += 64) {
        const int cnt = min(len - base, 64);
        int msrc = (lane < cnt) ? eidx[e0 + base + lane] : 0;
        int k = 0;
        for (; k + 32 <= cnt; k += 32) {
            uint4 u[8];
#pragma unroll
            for (int s = 0; s < 8; ++s) {
                int src = __shfl(msrc, k + s * 4 + g);
                u[s] = hq[(size_t)src * 16 + c16];
            }
#pragma unroll
            for (int s = 0; s < 8; ++s) {
                a0 += u2h(u[s].x); a1 += u2h(u[s].y);
                a2 += u2h(u[s].z); a3 += u2h(u[s].w);
            }
        }
        for (; k + 4 <= cnt; k += 4) {
            int src = __shfl(msrc, k + g);
            uint4 u = hq[(size_t)src * 16 + c16];
            a0 += u2h(u.x); a1 += u2h(u.y); a2 += u2h(u.z); a3 += u2h(u.w);
        }
        {
            int idx = k + g;
            int src = __shfl(msrc, min(idx, 63));
            if (idx < cnt) {
                uint4 u = hq[(size_t)src * 16 + c16];
                a0 += u2h(u.x); a1 += u2h(u.y); a2 += u2h(u.z); a3 += u2h(u.w);
            }
        }
    }
    // combine the 4 edge-groups
#pragma unroll
    for (int d = 16; d <= 32; d <<= 1) {
        a0 += u2h(__shfl_xor(__builtin_bit_cast(uint, a0), d));
        a1 += u2h(__shfl_xor(__builtin_bit_cast(uint, a1), d));
        a2 += u2h(__shfl_xor(__builtin_bit_cast(uint, a2), d));
        a3 += u2h(__shfl_xor(__builtin_bit_cast(uint, a3), d));
    }
    if (g == 0) {
        uint4 o;
        o.x = __builtin_bit_cast(uint, a0);
        o.y = __builtin_bit_cast(uint, a1);
        o.z = __builtin_bit_cast(uint, a2);
        o.w = __builtin_bit_cast(uint, a3);
        ((uint4*)agg)[(size_t)node * 16 + c16] = o;
    }
}

// ---------------------------------------------------------------- weight fragment prep
// WF layout: [half][kt 0..7][ct 0..3][lane 0..63][j 0..7]  (f16)
// frag element = W_half[ct*32 + (lane&31)][kt*16 + (lane>>5)*8 + j]
__global__ void wf_prep_kernel(const float* __restrict__ W0, const float* __restrict__ W1,
                               const float* __restrict__ W2, const float* __restrict__ W3,
                               ushort* __restrict__ WF2, ushort* __restrict__ WF3) {
    int i = blockIdx.x * 256 + threadIdx.x;   // 65536 threads
    const float* Ws[4] = {W0, W1, W2, W3};
    int mat = i >> 14;
    int m = i & 16383;
    int j = m & 7, lane = (m >> 3) & 63, ct = (m >> 9) & 3, kt = (m >> 11) & 7;
    int row = ct * 32 + (lane & 31);
    int col = kt * 16 + ((lane >> 5) * 8) + j;
    float v = Ws[mat][row * 128 + col];
    ushort* dstp = (mat < 2) ? WF2 : WF3;
    dstp[(mat & 1) * 16384 + m] = f2h(v);
}

// ---------------------------------------------------------------- fused conv via MFMA (f16)
template <int RELU>
__global__ __launch_bounds__(256) void conv_mfma_kernel(
    const short* __restrict__ agg, const short* __restrict__ hin,
    const short* __restrict__ WF,
    const float* __restrict__ brel, const float* __restrict__ gamma,
    const float* __restrict__ beta, const float* __restrict__ mean,
    const float* __restrict__ var,
    ushort* __restrict__ hout, int n) {
    const int lane = threadIdx.x & 63;
    const int wt = blockIdx.x * 4 + (threadIdx.x >> 6);
    const int node0 = wt * 32;
    if (node0 >= n) return;
    const int rowA = node0 + (lane & 31);
    const int arow = (rowA < n) ? rowA : (n - 1);
    const int koff = (lane >> 5) * 8;

    f32x16 acc[4];
#pragma unroll
    for (int c = 0; c < 4; ++c) acc[c] = (f32x16)(0.0f);

#pragma unroll
    for (int half = 0; half < 2; ++half) {
        const short* A = (half ? hin : agg) + (size_t)arow * 128 + koff;
        const short* B0 = WF + half * 16384 + lane * 8;
#pragma unroll
        for (int kt = 0; kt < 8; ++kt) {
            f16x8 a = __builtin_bit_cast(f16x8, *(const short8*)(A + kt * 16));
            const short* Bp = B0 + kt * 2048;
#pragma unroll
            for (int ct = 0; ct < 4; ++ct) {
                f16x8 b = __builtin_bit_cast(f16x8, *(const short8*)(Bp + ct * 512));
                acc[ct] = __builtin_amdgcn_mfma_f32_32x32x16_f16(a, b, acc[ct], 0, 0, 0);
            }
        }
    }

#pragma unroll
    for (int ct = 0; ct < 4; ++ct) {
        int c = ct * 32 + (lane & 31);
        float s = gamma[c] * rsqrtf(var[c] + EPS);
        float t = beta[c] - mean[c] * s + brel[c] * s;
#pragma unroll
        for (int r = 0; r < 16; ++r) {
            int row = (r & 3) + 8 * (r >> 2) + 4 * (lane >> 5);
            int node = node0 + row;
            if (node < n) {
                float v = acc[ct][r] * s + t;
                if (RELU) v = fmaxf(v, 0.f);
                hout[(size_t)node * 128 + c] = f2h(v);
            }
        }
    }
}

// ---------------------------------------------------------------- pooling (batch sorted)
// fold W_out dot into the scan: per wave, per-graph scalar accumulator
__global__ __launch_bounds__(256) void pool_kernel(const ushort* __restrict__ h,
                                                   const int* __restrict__ batch,
                                                   const float* __restrict__ Wout,
                                                   float* __restrict__ gscal,
                                                   int* __restrict__ gcnt, int n) {
    const int wv = blockIdx.x * 4 + (threadIdx.x >> 6);
    const int lane = threadIdx.x & 63;
    const int base = wv * 64;
    if (base >= n) return;
    const int end = min(base + 64, n);
    const uint* hu = (const uint*)h;
    const float w0 = Wout[lane * 2], w1 = Wout[lane * 2 + 1];
    float s = 0.f;
    int cur = batch[base], cl = 0;

    auto accum = [&](uint u) {
        half2v hv = u2h(u);
        s += (float)hv[0] * w0 + (float)hv[1] * w1;
        cl++;
    };
    auto flush = [&](int g) {
        float r = s;
#pragma unroll
        for (int d = 1; d < 64; d <<= 1) r += __shfl_xor(r, d);
        if (lane == 0) { atomicAdd(&gscal[g], r); atomicAdd(&gcnt[g], cl); }
        s = 0.f; cl = 0;
    };

    int i = base;
    for (; i + 4 <= end; i += 4) {
        int b3 = batch[i + 3];
        uint u0 = hu[(size_t)i * 64 + lane];
        uint u1 = hu[(size_t)(i + 1) * 64 + lane];
        uint u2 = hu[(size_t)(i + 2) * 64 + lane];
        uint u3 = hu[(size_t)(i + 3) * 64 + lane];
        if (b3 == cur) {
            accum(u0); accum(u1); accum(u2); accum(u3);
        } else {
            int bb[4] = {batch[i], batch[i + 1], batch[i + 2], b3};
            uint uu[4] = {u0, u1, u2, u3};
            for (int k = 0; k < 4; ++k) {
                if (bb[k] != cur) { flush(cur); cur = bb[k]; }
                accum(uu[k]);
            }
        }
    }
    for (; i < end; ++i) {
        int g = batch[i];
        if (g != cur) { flush(cur); cur = g; }
        accum(hu[(size_t)i * 64 + lane]);
    }
    flush(cur);
}

__global__ void out_kernel(const float* __restrict__ gscal, const int* __restrict__ gcnt,
                           const float* __restrict__ bout, float* __restrict__ out, int G) {
    int g = threadIdx.x;
    if (g < G) out[g] = gscal[g] / fmaxf((float)gcnt[g], 1.0f) + bout[0];
}

// ---------------------------------------------------------------- launch
extern "C" void kernel_launch(void* const* d_in, const int* in_sizes, int n_in,
                              void* d_out, int out_size, void* d_ws, size_t ws_size,
                              hipStream_t stream) {
    const int N = in_sizes[0];            // 100000 (< 2^17, required by stage packing)
    const int E = in_sizes[1] / 2;
    const int G = 64;

    const float* x     = (const float*)d_in[0];
    const int*   ei    = (const int*)d_in[1];
    const int*   batch = (const int*)d_in[2];
    const int*   src   = ei;
    const int*   dst   = ei + E;

    const float* Wrel1 = (const float*)d_in[3];
    const float* brel1 = (const float*)d_in[4];
    const float* Wroot1= (const float*)d_in[5];
    const float* g1    = (const float*)d_in[6];
    const float* be1   = (const float*)d_in[7];
    const float* m1    = (const float*)d_in[8];
    const float* v1    = (const float*)d_in[9];
    const float* Wrel2 = (const float*)d_in[10];
    const float* brel2 = (const float*)d_in[11];
    const float* Wroot2= (const float*)d_in[12];
    const float* g2    = (const float*)d_in[13];
    const float* be2   = (const float*)d_in[14];
    const float* m2    = (const float*)d_in[15];
    const float* v2    = (const float*)d_in[16];
    const float* Wrel3 = (const float*)d_in[17];
    const float* brel3 = (const float*)d_in[18];
    const float* Wroot3= (const float*)d_in[19];
    const float* g3    = (const float*)d_in[20];
    const float* be3   = (const float*)d_in[21];
    const float* m3    = (const float*)d_in[22];
    const float* v3    = (const float*)d_in[23];
    const float* Wout  = (const float*)d_in[24];
    const float* bout  = (const float*)d_in[25];

    float* out = (float*)d_out;

    // workspace carve (512B aligned)
    char* w = (char*)d_ws;
    auto alloc = [&](size_t bytes) { char* p = w; w += (bytes + 511) & ~(size_t)511; return p; };
    int*    rowptr = (int*)alloc((size_t)(N + 1) * 4);
    int*    bcnt   = (int*)alloc(NBMAX * 4);
    int*    gcur   = (int*)alloc(NBMAX * 4);
    uint*   stage  = (uint*)alloc((size_t)E * 4);
    int*    eidx   = (int*)alloc((size_t)E * 4);
    ushort* hA     = (ushort*)alloc((size_t)N * 128 * 2);
    ushort* hB     = (ushort*)alloc((size_t)N * 128 * 2);
    ushort* aggb   = (ushort*)alloc((size_t)N * 128 * 2);
    ushort* WF2    = (ushort*)alloc(32768 * 2);
    ushort* WF3    = (ushort*)alloc(32768 * 2);
    float*  gscal  = (float*)alloc((size_t)G * 4);
    int*    gcnt   = (int*)alloc((size_t)G * 4);

    const int NB   = (N >> BSH) + 1;      // 391 buckets of 256 dsts
    const int eBlk = (E + 8191) / 8192;

    hipMemsetAsync(bcnt, 0, NBMAX * 4, stream);
    hipMemsetAsync(gscal, 0, (size_t)G * 4, stream);
    hipMemsetAsync(gcnt, 0, (size_t)G * 4, stream);

    // CSR build: bucket count -> scan -> scatter -> per-bucket finalize
    bucket_count_kernel<<<eBlk, 256, 0, stream>>>(dst, bcnt, E, NB);
    scan_gcur_kernel<<<1, 512, 0, stream>>>(bcnt, gcur, NB);
    bucket_scatter_kernel<<<eBlk, 256, 0, stream>>>(src, dst, gcur, stage, E, NB);
    bucket_final_kernel<<<NB, 256, 0, stream>>>(stage, gcur, rowptr, eidx, N);

    // weight fragments
    wf_prep_kernel<<<256, 256, 0, stream>>>(Wrel2, Wroot2, Wrel3, Wroot3, WF2, WF3);

    // layer 1 (Cin=1), gather+BN+relu fused
    layer1_fused_kernel<<<(N + 15) / 16, 256, 0, stream>>>(x, rowptr, eidx, Wrel1, brel1,
                                                           Wroot1, g1, be1, m1, v1, hA, N);

    const int nwt     = (N + 31) / 32;
    const int convBlk = (nwt + 3) / 4;

    // layer 2
    gather_f16_kernel<<<(N + 3) / 4, 256, 0, stream>>>(hA, rowptr, eidx, aggb, N);
    conv_mfma_kernel<1><<<convBlk, 256, 0, stream>>>((const short*)aggb, (const short*)hA,
                                                     (const short*)WF2, brel2, g2, be2, m2, v2,
                                                     hB, N);

    // layer 3
    gather_f16_kernel<<<(N + 3) / 4, 256, 0, stream>>>(hB, rowptr, eidx, aggb, N);
    conv_mfma_kernel<0><<<convBlk, 256, 0, stream>>>((const short*)aggb, (const short*)hB,
                                                     (const short*)WF3, brel3, g3, be3, m3, v3,
                                                     hA, N);

    // pool + output
    pool_kernel<<<(N + 255) / 256, 256, 0, stream>>>(hA, batch, Wout, gscal, gcnt, N);
    out_kernel<<<1, 64, 0, stream>>>(gscal, gcnt, bout, out, G);
}